// Round 10
// baseline (274.932 us; speedup 1.0000x reference)
//
#include <hip/hip_runtime.h>
#include <stdint.h>

typedef __attribute__((ext_vector_type(8))) short bf16x8;
typedef __attribute__((ext_vector_type(4))) float f32x4;

#define MFMA16(a, b, c) __builtin_amdgcn_mfma_f32_16x16x32_bf16((a), (b), (c), 0, 0, 0)

static __device__ __forceinline__ unsigned f2bf(float f) {
  union { float f; unsigned u; } cv;
  cv.f = f;
  return (cv.u + 0x7fffu + ((cv.u >> 16) & 1u)) >> 16;
}

#define BATCH 8192
#define ROWD  2128
#define HID   512
#define LATD  256
#define KC1   272            // 8-elem k-chunks for layer 1 (272*8 = 2176, zero-padded)
#define KQ    544            // floats per K-quarter
#define KCQ   68             // k-chunks per quarter
#define NTQ   17             // 32-k tiles per quarter
#define ABUF  (KCQ * 64 * 8) // ushorts per A LDS buffer (34816)
#define HSL_TW (BATCH * HID) // ushorts per tower in h_sl

// ---------- prep: k-chunked transpose-cast ----------
__global__ __launch_bounds__(256) void ASAECF_tcast(
    const float* __restrict__ in0, const float* __restrict__ in1,
    unsigned short* __restrict__ out, int N, int lgN, int Kin, int KC, int perm)
{
  const float* __restrict__ in = blockIdx.z ? in1 : in0;
  unsigned short* __restrict__ o = out + (size_t)blockIdx.z * KC * N * 8;
  const int s = blockIdx.x * 256 + threadIdx.x;   // slot index
  const int kc = s >> lgN, n = s & (N - 1);
  unsigned short v[8];
#pragma unroll
  for (int e = 0; e < 8; ++e) {
    const int k = kc * 8 + e;
    float f = 0.0f;
    if (k < Kin) {
      const int src = perm ? (k < 128 ? k + 2000 : k - 128) : k;
      f = in[(size_t)src * N + n];
    }
    v[e] = (unsigned short)f2bf(f);
  }
  *(uint4*)(o + (size_t)s * 8) = *(const uint4*)v;
}

// ---------- GEMM1: h = relu(gather(look) @ W1p + b1) ----------
// Producer/consumer wave specialization. 576 threads:
//   wave 8 (producer): streams the block's 64 gathered rows CONTIGUOUSLY
//     (1-KB wave-instrs, K-quarter granularity) into double-buffered LDS
//     (bf16, k-chunked fragment layout, XOR-swizzled rows).
//   waves 0-7 (consumers): pure MFMA k-loop, B reg-prefetch from L2 slab,
//     swizzled ds_read_b128 for A fragments. Never issue gather loads.
// BM=64, BN=512 (full N -> gather read once, 139 MB HBM), BK=32.
// Grid = 128 mb x 2 towers = 256 blocks. 1 barrier per K-quarter (5 total).
__global__ __launch_bounds__(576) void ASAECF_gemm1(
    const int* __restrict__ x,
    const float* __restrict__ ulook, const float* __restrict__ ilook,
    const unsigned short* __restrict__ w1s,   // [2][KC1][512][8]
    const float* __restrict__ ub1, const float* __restrict__ ib1,
    unsigned short* __restrict__ hsl)         // [2][chunk64][kc][row64][8]
{
  extern __shared__ unsigned short Asl[];     // 2 x [68 kc][64 row][8] = 139,264 B

  // tower<->XCD partition: XCDs 0-3 -> tower 0, XCDs 4-7 -> tower 1
  const int bid   = blockIdx.x;             // 0..255
  const int xcd   = bid & 7;
  const int tower = xcd >> 2;
  const int mb    = (xcd & 3) * 32 + (bid >> 3);   // 0..127

  const float* __restrict__ look = tower ? ilook : ulook;
  const unsigned short* __restrict__ w1 = w1s + (size_t)tower * KC1 * HID * 8;
  const float* __restrict__ b1 = tower ? ib1 : ub1;
  unsigned short* __restrict__ hout = hsl + (size_t)tower * HSL_TW;

  const int tid  = threadIdx.x;
  const int lane = tid & 63, wid = tid >> 6;  // wid 0..8
  const int fr   = lane & 15, fq = lane >> 4;
  const int row0 = mb * 64;

  // producer: stage quarter q into buffer buf
  auto stage = [&](int q, int buf) {
    unsigned short* Aq = Asl + buf * ABUF;
#pragma unroll 4
    for (int r = 0; r < 64; ++r) {
      const long long ab = (long long)x[(row0 + r) * 2 + tower] * ROWD;
      const float* rp = look + ab + q * KQ;
#pragma unroll
      for (int c = 0; c < 3; ++c) {
        const int kl = c * 256 + lane * 4;
        if (c < 2 || lane < 8) {               // 544 floats = 2 full + 1/8 chunk
          f32x4 v = {0.0f, 0.0f, 0.0f, 0.0f};
          if (q * KQ + kl + 4 <= ROWD) v = *(const f32x4*)(rp + kl);
          uint2 p;
          p.x = f2bf(v[0]) | (f2bf(v[1]) << 16);
          p.y = f2bf(v[2]) | (f2bf(v[3]) << 16);
          const int kc = kl >> 3;              // c*32 + (lane>>1)
          *(uint2*)&Aq[(kc * 64 + (r ^ (kc & 7))) * 8 + (lane & 1) * 4] = p;
        }
      }
    }
  };

  // consumer state
  int boff[4];
#pragma unroll
  for (int n = 0; n < 4; ++n)
    boff[n] = (fq * 512 + wid * 64 + n * 16 + fr) * 8;
  f32x4 acc[4][4] = {};

  // prologue: producer stages quarter 0; consumers wait
  if (wid == 8) stage(0, 0);
  __syncthreads();

  for (int q = 0; q < 4; ++q) {
    if (wid == 8) {
      if (q < 3) stage(q + 1, (q + 1) & 1);
    } else {
      // ---- consumer: 17 k-tiles from buf q&1, B reg-prefetch ----
      const unsigned short* bq = w1 + (size_t)(q * NTQ) * (4 * 512 * 8);
      const unsigned short* Aq = Asl + (q & 1) * ABUF;
      bf16x8 bgc[4], bgn[4];
#pragma unroll
      for (int n = 0; n < 4; ++n) bgc[n] = *(const bf16x8*)(bq + boff[n]);
      for (int tt = 0; tt < NTQ; ++tt) {
        const int tn = (q * NTQ + tt + 1 <= 67) ? tt + 1 : tt;   // clamp tail
        const unsigned short* bpn = bq + (size_t)tn * (4 * 512 * 8);
#pragma unroll
        for (int n = 0; n < 4; ++n) bgn[n] = *(const bf16x8*)(bpn + boff[n]);

        bf16x8 af[4];
#pragma unroll
        for (int m = 0; m < 4; ++m) {
          const int kc = tt * 4 + fq;
          af[m] = *(const bf16x8*)&Aq[(kc * 64 + ((m * 16 + fr) ^ (kc & 7))) * 8];
        }
#pragma unroll
        for (int n = 0; n < 4; ++n)
#pragma unroll
          for (int m = 0; m < 4; ++m)
            acc[m][n] = MFMA16(af[m], bgc[n], acc[m][n]);

#pragma unroll
        for (int n = 0; n < 4; ++n) bgc[n] = bgn[n];
      }
    }
    __syncthreads();
  }

  // epilogue (consumers): bias + relu + store h in k-chunked slot layout
  if (wid < 8) {
#pragma unroll
    for (int n = 0; n < 4; ++n) {
      const int col = wid * 64 + n * 16 + fr;
      const int kc = col >> 3, e = col & 7;
      const float bb = b1[col];
      unsigned short* hb = hout + (((size_t)mb * 64 + kc) * 64) * 8 + e;
#pragma unroll
      for (int m = 0; m < 4; ++m)
#pragma unroll
        for (int i = 0; i < 4; ++i) {
          const int row = m * 16 + fq * 4 + i;
          const float v = fmaxf(acc[m][n][i] + bb, 0.0f);
          hb[row * 8] = (unsigned short)f2bf(v);
        }
    }
  }
}

// ---------- GEMM2 + dot, fully fused, no LDS staging ----------
__global__ __launch_bounds__(512, 2) void ASAECF_gemm2dot(
    const unsigned short* __restrict__ hsl,   // [2][chunk64][kc][row64][8]
    const unsigned short* __restrict__ w2s,   // [2][64][256][8]
    const float* __restrict__ ub2, const float* __restrict__ ib2,
    float* __restrict__ out)
{
  const int tid  = threadIdx.x;
  const int lane = tid & 63, wid = tid >> 6;
  const int fr   = lane & 15, fq = lane >> 4;
  const int rb   = blockIdx.x;          // 32-row block
  const int row0 = rb * 32;

  const unsigned short* __restrict__ hu = hsl;
  const unsigned short* __restrict__ hv = hsl + (size_t)HSL_TW;
  const size_t abase = ((size_t)(rb >> 1) * 64) * 64 * 8;
  const int lrow0 = (rb & 1) * 32;

  f32x4 au[2][2] = {}, av[2][2] = {};

#pragma unroll
  for (int t = 0; t < 8; ++t) {
#pragma unroll
    for (int s = 0; s < 2; ++s) {
      const int kc = t * 8 + s * 4 + fq;
      bf16x8 a_u[2], a_v[2], b_u[2], b_v[2];
#pragma unroll
      for (int m = 0; m < 2; ++m) {
        const size_t off = abase + ((size_t)kc * 64 + lrow0 + m * 16 + fr) * 8;
        a_u[m] = *(const bf16x8*)(hu + off);
        a_v[m] = *(const bf16x8*)(hv + off);
      }
#pragma unroll
      for (int n = 0; n < 2; ++n) {
        const int col = wid * 32 + n * 16 + fr;
        const size_t offb = ((size_t)kc * 256 + col) * 8;
        b_u[n] = *(const bf16x8*)(w2s + offb);
        b_v[n] = *(const bf16x8*)(w2s + (size_t)64 * 256 * 8 + offb);
      }
#pragma unroll
      for (int m = 0; m < 2; ++m)
#pragma unroll
        for (int n = 0; n < 2; ++n) {
          au[m][n] = MFMA16(a_u[m], b_u[n], au[m][n]);
          av[m][n] = MFMA16(a_v[m], b_v[n], av[m][n]);
        }
    }
  }

  // bias + per-row dot + reduction
  __shared__ float red[8][32];
  float bu[2], bv[2];
#pragma unroll
  for (int n = 0; n < 2; ++n) {
    const int col = wid * 32 + n * 16 + fr;
    bu[n] = ub2[col];
    bv[n] = ib2[col];
  }
#pragma unroll
  for (int m = 0; m < 2; ++m)
#pragma unroll
    for (int i = 0; i < 4; ++i) {
      float p = 0.0f;
#pragma unroll
      for (int n = 0; n < 2; ++n)
        p += (au[m][n][i] + bu[n]) * (av[m][n][i] + bv[n]);
      p += __shfl_xor(p, 1, 64);
      p += __shfl_xor(p, 2, 64);
      p += __shfl_xor(p, 4, 64);
      p += __shfl_xor(p, 8, 64);
      if (fr == 0) red[wid][m * 16 + fq * 4 + i] = p;
    }
  __syncthreads();
  if (tid < 32) {
    float s = 0.0f;
#pragma unroll
    for (int w = 0; w < 8; ++w) s += red[w][tid];
    out[row0 + tid] = s;
  }
}

extern "C" void kernel_launch(void* const* d_in, const int* in_sizes, int n_in,
                              void* d_out, int out_size, void* d_ws, size_t ws_size,
                              hipStream_t stream) {
  (void)in_sizes; (void)n_in; (void)out_size; (void)ws_size;
  const int*   x     = (const int*)d_in[0];
  const float* ulook = (const float*)d_in[1];
  const float* ilook = (const float*)d_in[2];
  const float* uW1   = (const float*)d_in[3];
  const float* ub1   = (const float*)d_in[4];
  const float* uW2   = (const float*)d_in[5];
  const float* ub2   = (const float*)d_in[6];
  const float* iW1   = (const float*)d_in[7];
  const float* ib1   = (const float*)d_in[8];
  const float* iW2   = (const float*)d_in[9];
  const float* ib2   = (const float*)d_in[10];
  float* out = (float*)d_out;

  // workspace layout (bytes):
  //   w1s: [2][272][512][8] bf16 = 4,456,448
  //   w2s: [2][64][256][8]  bf16 =   524,288  @ 4,456,448
  //   hsl: [2][8192*512]    bf16 = 16,777,216 @ 4,980,736
  char* ws = (char*)d_ws;
  unsigned short* w1s = (unsigned short*)(ws);
  unsigned short* w2s = (unsigned short*)(ws + 4456448);
  unsigned short* hsl = (unsigned short*)(ws + 4980736);

  ASAECF_tcast<<<dim3(544, 1, 2), 256, 0, stream>>>(uW1, iW1, w1s, 512, 9, ROWD, KC1, 1);
  ASAECF_tcast<<<dim3(64, 1, 2),  256, 0, stream>>>(uW2, iW2, w2s, 256, 8, HID, 64, 0);
  ASAECF_gemm1<<<dim3(256), 576, 139264, stream>>>(x, ulook, ilook, w1s, ub1, ib1, hsl);
  ASAECF_gemm2dot<<<dim3(256), 512, 0, stream>>>(hsl, w2s, ub2, ib2, out);
}

// Round 11
// 95.166 us; speedup vs baseline: 2.8890x; 2.8890x over previous
//
#include <hip/hip_runtime.h>
#include <stdint.h>

typedef __attribute__((ext_vector_type(8))) short bf16x8;
typedef __attribute__((ext_vector_type(4))) float f32x4;

#define MFMA16(a, b, c) __builtin_amdgcn_mfma_f32_16x16x32_bf16((a), (b), (c), 0, 0, 0)

static __device__ __forceinline__ unsigned f2bf(float f) {
  union { float f; unsigned u; } cv;
  cv.f = f;
  return (cv.u + 0x7fffu + ((cv.u >> 16) & 1u)) >> 16;
}

#define BATCH 8192
#define ROWD  2128
#define HID   512
#define LATD  256
#define KC1   272            // 8-elem k-chunks for layer 1 (272*8 = 2176, zero-padded)
#define NT1   68             // 32-k tiles (68*32 = 2176; trailing tiles zero-padded)
#define HSL_TW (BATCH * HID) // ushorts per tower in h_sl

// ---------- prep: k-chunked transpose-cast ----------
__global__ __launch_bounds__(256) void ASAECF_tcast(
    const float* __restrict__ in0, const float* __restrict__ in1,
    unsigned short* __restrict__ out, int N, int lgN, int Kin, int KC, int perm)
{
  const float* __restrict__ in = blockIdx.z ? in1 : in0;
  unsigned short* __restrict__ o = out + (size_t)blockIdx.z * KC * N * 8;
  const int s = blockIdx.x * 256 + threadIdx.x;   // slot index
  const int kc = s >> lgN, n = s & (N - 1);
  unsigned short v[8];
#pragma unroll
  for (int e = 0; e < 8; ++e) {
    const int k = kc * 8 + e;
    float f = 0.0f;
    if (k < Kin) {
      const int src = perm ? (k < 128 ? k + 2000 : k - 128) : k;
      f = in[(size_t)src * N + n];
    }
    v[e] = (unsigned short)f2bf(f);
  }
  *(uint4*)(o + (size_t)s * 8) = *(const uint4*)v;
}

// ---------- GEMM1: h = relu(gather(look) @ W1p + b1) ----------
// BM=64, BN=256, BK=32. 512 threads = 8 waves (2M x 4N), wave tile 32x64.
// Grid = 128 mb x 2 nh x 2 towers = 512 blocks -> TWO independent blocks/CU
// (launch_bounds caps VGPR for 4 waves/SIMD): one block's barrier/gather
// stall hides under the other block's MFMA + load issue.
__global__ __launch_bounds__(512, 4) void ASAECF_gemm1(
    const int* __restrict__ x,
    const float* __restrict__ ulook, const float* __restrict__ ilook,
    const unsigned short* __restrict__ w1s,   // [2][KC1][512][8]
    const float* __restrict__ ub1, const float* __restrict__ ib1,
    unsigned short* __restrict__ hsl)         // [2][chunk64][kc][row64][8]
{
  // bid -> xcd = bid&7; tower = xcd>>2; idx = bid>>3 (0..63);
  // nh = idx&1 (pair adjacent on same XCD); mb = (xcd&3)*32 + (idx>>1) (0..127)
  const int bid   = blockIdx.x;             // 0..511
  const int xcd   = bid & 7;
  const int idx   = bid >> 3;               // 0..63
  const int tower = xcd >> 2;
  const int nh    = idx & 1;
  const int mb    = (xcd & 3) * 32 + (idx >> 1);   // 0..127

  const float* __restrict__ look = tower ? ilook : ulook;
  const unsigned short* __restrict__ w1 = w1s + (size_t)tower * KC1 * HID * 8;
  const float* __restrict__ b1 = tower ? ib1 : ub1;
  unsigned short* __restrict__ hout = hsl + (size_t)tower * HSL_TW;

  __shared__ unsigned short Ab[2][64 * 40];   // 64 rows x 32 k, 80-B padded rows

  const int tid  = threadIdx.x;
  const int lane = tid & 63, wid = tid >> 6;
  const int wm   = wid >> 2, wn = wid & 3;    // wave tile: rows wm*32, cols wn*64
  const int fr   = lane & 15, fq = lane >> 4;
  const int row0 = mb * 64;

  // A staging: thread -> (row ar, 4 consecutive k at ak)
  const int ar = tid >> 3, ak = (tid & 7) * 4;
  const long long arow = (long long)x[(row0 + ar) * 2 + tower] * ROWD + ak;

  // B fragment offsets within one k-tile slab (4*512*8 ushorts)
  int boff[4];
#pragma unroll
  for (int n = 0; n < 4; ++n)
    boff[n] = (fq * 512 + nh * 256 + wn * 64 + n * 16 + fr) * 8;

  auto loadA = [&](int tt) -> f32x4 {
    f32x4 v = {0.0f, 0.0f, 0.0f, 0.0f};
    if (tt * 32 + ak <= ROWD - 4)
      v = *(const f32x4*)(look + arow + tt * 32);
    return v;
  };
  auto writeA = [&](int buf, f32x4 v) {
    uint2 p;
    p.x = f2bf(v[0]) | (f2bf(v[1]) << 16);
    p.y = f2bf(v[2]) | (f2bf(v[3]) << 16);
    *(uint2*)&Ab[buf][ar * 40 + ak] = p;
  };

  f32x4 acc[2][4] = {};
  bf16x8 bgc[4], bgn[4];
  f32x4 rA0, rA1;

  // prologue: A(0) -> Ab[0]; A(1),A(2) in flight; B(0) in flight
  writeA(0, loadA(0));
  rA0 = loadA(1);
  rA1 = loadA(2);
#pragma unroll
  for (int n = 0; n < 4; ++n) bgc[n] = *(const bf16x8*)(w1 + boff[n]);

#pragma unroll 2
  for (int t = 0; t < NT1; ++t) {
    __syncthreads();   // Ab[t&1] ready
    const int cu = t & 1;

    // B prefetch for t+1 (stays in flight through this tile's MFMAs)
    const unsigned short* bpn = w1 + (size_t)(t + 1) * (4 * 512 * 8);
#pragma unroll
    for (int n = 0; n < 4; ++n) bgn[n] = *(const bf16x8*)(bpn + boff[n]);

    bf16x8 af[2];
#pragma unroll
    for (int m = 0; m < 2; ++m)
      af[m] = *(const bf16x8*)&Ab[cu][(wm * 32 + m * 16 + fr) * 40 + fq * 8];
#pragma unroll
    for (int n = 0; n < 4; ++n)
#pragma unroll
      for (int m = 0; m < 2; ++m)
        acc[m][n] = MFMA16(af[m], bgc[n], acc[m][n]);

    // deferred A write (loaded 2 tiles ago), then refill the pipe
    if (cu == 0) { writeA(1, rA0); rA0 = loadA(t + 3); }
    else         { writeA(0, rA1); rA1 = loadA(t + 3); }

#pragma unroll
    for (int n = 0; n < 4; ++n) bgc[n] = bgn[n];
  }

  // epilogue: bias + relu + store h in k-chunked slot layout
#pragma unroll
  for (int n = 0; n < 4; ++n) {
    const int col = nh * 256 + wn * 64 + n * 16 + fr;
    const int kc = col >> 3, e = col & 7;
    const float bb = b1[col];
    unsigned short* hb = hout + (((size_t)mb * 64 + kc) * 64) * 8 + e;
#pragma unroll
    for (int m = 0; m < 2; ++m)
#pragma unroll
      for (int i = 0; i < 4; ++i) {
        const int row = wm * 32 + m * 16 + fq * 4 + i;   // within 64-row chunk
        const float v = fmaxf(acc[m][n][i] + bb, 0.0f);
        hb[row * 8] = (unsigned short)f2bf(v);
      }
  }
}

// ---------- GEMM2 + dot, fully fused, no LDS staging ----------
__global__ __launch_bounds__(512, 2) void ASAECF_gemm2dot(
    const unsigned short* __restrict__ hsl,   // [2][chunk64][kc][row64][8]
    const unsigned short* __restrict__ w2s,   // [2][64][256][8]
    const float* __restrict__ ub2, const float* __restrict__ ib2,
    float* __restrict__ out)
{
  const int tid  = threadIdx.x;
  const int lane = tid & 63, wid = tid >> 6;
  const int fr   = lane & 15, fq = lane >> 4;
  const int rb   = blockIdx.x;          // 32-row block
  const int row0 = rb * 32;

  const unsigned short* __restrict__ hu = hsl;
  const unsigned short* __restrict__ hv = hsl + (size_t)HSL_TW;
  const size_t abase = ((size_t)(rb >> 1) * 64) * 64 * 8;
  const int lrow0 = (rb & 1) * 32;

  f32x4 au[2][2] = {}, av[2][2] = {};

#pragma unroll
  for (int t = 0; t < 8; ++t) {
#pragma unroll
    for (int s = 0; s < 2; ++s) {
      const int kc = t * 8 + s * 4 + fq;
      bf16x8 a_u[2], a_v[2], b_u[2], b_v[2];
#pragma unroll
      for (int m = 0; m < 2; ++m) {
        const size_t off = abase + ((size_t)kc * 64 + lrow0 + m * 16 + fr) * 8;
        a_u[m] = *(const bf16x8*)(hu + off);
        a_v[m] = *(const bf16x8*)(hv + off);
      }
#pragma unroll
      for (int n = 0; n < 2; ++n) {
        const int col = wid * 32 + n * 16 + fr;
        const size_t offb = ((size_t)kc * 256 + col) * 8;
        b_u[n] = *(const bf16x8*)(w2s + offb);
        b_v[n] = *(const bf16x8*)(w2s + (size_t)64 * 256 * 8 + offb);
      }
#pragma unroll
      for (int m = 0; m < 2; ++m)
#pragma unroll
        for (int n = 0; n < 2; ++n) {
          au[m][n] = MFMA16(a_u[m], b_u[n], au[m][n]);
          av[m][n] = MFMA16(a_v[m], b_v[n], av[m][n]);
        }
    }
  }

  // bias + per-row dot + reduction
  __shared__ float red[8][32];
  float bu[2], bv[2];
#pragma unroll
  for (int n = 0; n < 2; ++n) {
    const int col = wid * 32 + n * 16 + fr;
    bu[n] = ub2[col];
    bv[n] = ib2[col];
  }
#pragma unroll
  for (int m = 0; m < 2; ++m)
#pragma unroll
    for (int i = 0; i < 4; ++i) {
      float p = 0.0f;
#pragma unroll
      for (int n = 0; n < 2; ++n)
        p += (au[m][n][i] + bu[n]) * (av[m][n][i] + bv[n]);
      p += __shfl_xor(p, 1, 64);
      p += __shfl_xor(p, 2, 64);
      p += __shfl_xor(p, 4, 64);
      p += __shfl_xor(p, 8, 64);
      if (fr == 0) red[wid][m * 16 + fq * 4 + i] = p;
    }
  __syncthreads();
  if (tid < 32) {
    float s = 0.0f;
#pragma unroll
    for (int w = 0; w < 8; ++w) s += red[w][tid];
    out[row0 + tid] = s;
  }
}

extern "C" void kernel_launch(void* const* d_in, const int* in_sizes, int n_in,
                              void* d_out, int out_size, void* d_ws, size_t ws_size,
                              hipStream_t stream) {
  (void)in_sizes; (void)n_in; (void)out_size; (void)ws_size;
  const int*   x     = (const int*)d_in[0];
  const float* ulook = (const float*)d_in[1];
  const float* ilook = (const float*)d_in[2];
  const float* uW1   = (const float*)d_in[3];
  const float* ub1   = (const float*)d_in[4];
  const float* uW2   = (const float*)d_in[5];
  const float* ub2   = (const float*)d_in[6];
  const float* iW1   = (const float*)d_in[7];
  const float* ib1   = (const float*)d_in[8];
  const float* iW2   = (const float*)d_in[9];
  const float* ib2   = (const float*)d_in[10];
  float* out = (float*)d_out;

  // workspace layout (bytes):
  //   w1s: [2][272][512][8] bf16 = 4,456,448
  //   w2s: [2][64][256][8]  bf16 =   524,288  @ 4,456,448
  //   hsl: [2][8192*512]    bf16 = 16,777,216 @ 4,980,736
  char* ws = (char*)d_ws;
  unsigned short* w1s = (unsigned short*)(ws);
  unsigned short* w2s = (unsigned short*)(ws + 4456448);
  unsigned short* hsl = (unsigned short*)(ws + 4980736);

  ASAECF_tcast<<<dim3(544, 1, 2), 256, 0, stream>>>(uW1, iW1, w1s, 512, 9, ROWD, KC1, 1);
  ASAECF_tcast<<<dim3(64, 1, 2),  256, 0, stream>>>(uW2, iW2, w2s, 256, 8, HID, 64, 0);
  ASAECF_gemm1<<<dim3(512), 512, 0, stream>>>(x, ulook, ilook, w1s, ub1, ib1, hsl);
  ASAECF_gemm2dot<<<dim3(256), 512, 0, stream>>>(hsl, w2s, ub2, ib2, out);
}

// Round 12
// 91.168 us; speedup vs baseline: 3.0157x; 1.0438x over previous
//
#include <hip/hip_runtime.h>
#include <stdint.h>

typedef __attribute__((ext_vector_type(8))) short bf16x8;
typedef __attribute__((ext_vector_type(4))) float f32x4;

#define MFMA16(a, b, c) __builtin_amdgcn_mfma_f32_16x16x32_bf16((a), (b), (c), 0, 0, 0)

static __device__ __forceinline__ unsigned f2bf(float f) {
  union { float f; unsigned u; } cv;
  cv.f = f;
  return (cv.u + 0x7fffu + ((cv.u >> 16) & 1u)) >> 16;
}

#define BATCH 8192
#define ROWD  2128
#define HID   512
#define LATD  256
#define KC1   272            // 8-elem k-chunks for layer 1 (272*8 = 2176, zero-padded)
#define NT1   68             // 32-k tiles (68*32 = 2176; trailing tiles zero-padded)
#define HSL_TW (BATCH * HID) // ushorts per tower in h_sl

// ---------- prep: k-chunked transpose-cast ----------
__global__ __launch_bounds__(256) void ASAECF_tcast(
    const float* __restrict__ in0, const float* __restrict__ in1,
    unsigned short* __restrict__ out, int N, int lgN, int Kin, int KC, int perm)
{
  const float* __restrict__ in = blockIdx.z ? in1 : in0;
  unsigned short* __restrict__ o = out + (size_t)blockIdx.z * KC * N * 8;
  const int s = blockIdx.x * 256 + threadIdx.x;   // slot index
  const int kc = s >> lgN, n = s & (N - 1);
  unsigned short v[8];
#pragma unroll
  for (int e = 0; e < 8; ++e) {
    const int k = kc * 8 + e;
    float f = 0.0f;
    if (k < Kin) {
      const int src = perm ? (k < 128 ? k + 2000 : k - 128) : k;
      f = in[(size_t)src * N + n];
    }
    v[e] = (unsigned short)f2bf(f);
  }
  *(uint4*)(o + (size_t)s * 8) = *(const uint4*)v;
}

// ---------- GEMM1: h = relu(gather(look) @ W1p + b1) ----------
// BM=128, BN=256 (nh half), BK=32. SINGLE CHANGE vs R9 (80.5us best):
// 1024 threads = 16 waves (4M x 4N, wave tile 32x64) instead of 512/8 ->
// occupancy 2 -> 4 waves/SIMD so barrier/memory waits are hideable.
// Grid = 64 mb x 2 nh x 2 towers = 256 blocks (1/CU). Traffic identical to R9.
__global__ __launch_bounds__(1024) void ASAECF_gemm1(
    const int* __restrict__ x,
    const float* __restrict__ ulook, const float* __restrict__ ilook,
    const unsigned short* __restrict__ w1s,   // [2][KC1][512][8]
    const float* __restrict__ ub1, const float* __restrict__ ib1,
    unsigned short* __restrict__ hsl)         // [2][chunk64][kc][row64][8]
{
  // bid -> xcd = bid&7; tower = xcd>>2; idx = bid>>3 (0..31);
  // nh = idx&1 (pair adjacent on same XCD); mb = (xcd&3)*16 + (idx>>1) (0..63)
  const int bid   = blockIdx.x;             // 0..255
  const int xcd   = bid & 7;
  const int idx   = bid >> 3;               // 0..31
  const int tower = xcd >> 2;
  const int nh    = idx & 1;
  const int mb    = (xcd & 3) * 16 + (idx >> 1);   // 0..63

  const float* __restrict__ look = tower ? ilook : ulook;
  const unsigned short* __restrict__ w1 = w1s + (size_t)tower * KC1 * HID * 8;
  const float* __restrict__ b1 = tower ? ib1 : ub1;
  unsigned short* __restrict__ hout = hsl + (size_t)tower * HSL_TW;

  __shared__ unsigned short Ab[2][128 * 40];  // 128 rows x 32 k, 80-B padded rows

  const int tid  = threadIdx.x;
  const int lane = tid & 63, wid = tid >> 6;  // wid 0..15
  const int wm   = wid >> 2, wn = wid & 3;    // wave tile: rows wm*32, cols wn*64
  const int fr   = lane & 15, fq = lane >> 4;
  const int row0 = mb * 128;

  // A staging: thread -> (row ar, 4 consecutive k at ak)
  const int ar = tid >> 3, ak = (tid & 7) * 4;
  const long long arow = (long long)x[(row0 + ar) * 2 + tower] * ROWD + ak;

  // B fragment offsets within one k-tile slab (4*512*8 ushorts)
  int boff[4];
#pragma unroll
  for (int n = 0; n < 4; ++n)
    boff[n] = (fq * 512 + nh * 256 + wn * 64 + n * 16 + fr) * 8;

  auto loadA = [&](int tt) -> f32x4 {
    f32x4 v = {0.0f, 0.0f, 0.0f, 0.0f};
    if (tt * 32 + ak <= ROWD - 4)
      v = *(const f32x4*)(look + arow + tt * 32);
    return v;
  };
  auto writeA = [&](int buf, f32x4 v) {
    uint2 p;
    p.x = f2bf(v[0]) | (f2bf(v[1]) << 16);
    p.y = f2bf(v[2]) | (f2bf(v[3]) << 16);
    *(uint2*)&Ab[buf][ar * 40 + ak] = p;
  };

  f32x4 acc[2][4] = {};
  bf16x8 bgc[4], bgn[4];
  f32x4 rA0, rA1;

  // prologue: A(0) -> Ab[0]; A(1),A(2) in flight; B(0) in flight
  writeA(0, loadA(0));
  rA0 = loadA(1);
  rA1 = loadA(2);
#pragma unroll
  for (int n = 0; n < 4; ++n) bgc[n] = *(const bf16x8*)(w1 + boff[n]);

#pragma unroll 2
  for (int t = 0; t < NT1; ++t) {
    __syncthreads();   // Ab[t&1] ready
    const int cu = t & 1;

    // B prefetch for t+1 (stays in flight through this tile's MFMAs)
    const unsigned short* bpn = w1 + (size_t)(t + 1) * (4 * 512 * 8);
#pragma unroll
    for (int n = 0; n < 4; ++n) bgn[n] = *(const bf16x8*)(bpn + boff[n]);

    bf16x8 af[2];
#pragma unroll
    for (int m = 0; m < 2; ++m)
      af[m] = *(const bf16x8*)&Ab[cu][(wm * 32 + m * 16 + fr) * 40 + fq * 8];
#pragma unroll
    for (int n = 0; n < 4; ++n)
#pragma unroll
      for (int m = 0; m < 2; ++m)
        acc[m][n] = MFMA16(af[m], bgc[n], acc[m][n]);

    // deferred A write (loaded 2 tiles ago), then refill the pipe
    if (cu == 0) { writeA(1, rA0); rA0 = loadA(t + 3); }
    else         { writeA(0, rA1); rA1 = loadA(t + 3); }

#pragma unroll
    for (int n = 0; n < 4; ++n) bgc[n] = bgn[n];
  }

  // epilogue: bias + relu + store h in k-chunked slot layout
#pragma unroll
  for (int n = 0; n < 4; ++n) {
    const int col = nh * 256 + wn * 64 + n * 16 + fr;
    const int kc = col >> 3, e = col & 7;
    const float bb = b1[col];
#pragma unroll
    for (int m = 0; m < 2; ++m)
#pragma unroll
      for (int i = 0; i < 4; ++i) {
        const int rowib = wm * 32 + m * 16 + fq * 4 + i;   // 0..127 within block
        const int chunk = mb * 2 + (rowib >> 6);
        const int row = rowib & 63;
        const float v = fmaxf(acc[m][n][i] + bb, 0.0f);
        hout[(((size_t)chunk * 64 + kc) * 64 + row) * 8 + e] = (unsigned short)f2bf(v);
      }
  }
}

// ---------- GEMM2 + dot, fully fused, no LDS staging ----------
__global__ __launch_bounds__(512, 2) void ASAECF_gemm2dot(
    const unsigned short* __restrict__ hsl,   // [2][chunk64][kc][row64][8]
    const unsigned short* __restrict__ w2s,   // [2][64][256][8]
    const float* __restrict__ ub2, const float* __restrict__ ib2,
    float* __restrict__ out)
{
  const int tid  = threadIdx.x;
  const int lane = tid & 63, wid = tid >> 6;
  const int fr   = lane & 15, fq = lane >> 4;
  const int rb   = blockIdx.x;          // 32-row block
  const int row0 = rb * 32;

  const unsigned short* __restrict__ hu = hsl;
  const unsigned short* __restrict__ hv = hsl + (size_t)HSL_TW;
  const size_t abase = ((size_t)(rb >> 1) * 64) * 64 * 8;
  const int lrow0 = (rb & 1) * 32;

  f32x4 au[2][2] = {}, av[2][2] = {};

#pragma unroll
  for (int t = 0; t < 8; ++t) {
#pragma unroll
    for (int s = 0; s < 2; ++s) {
      const int kc = t * 8 + s * 4 + fq;
      bf16x8 a_u[2], a_v[2], b_u[2], b_v[2];
#pragma unroll
      for (int m = 0; m < 2; ++m) {
        const size_t off = abase + ((size_t)kc * 64 + lrow0 + m * 16 + fr) * 8;
        a_u[m] = *(const bf16x8*)(hu + off);
        a_v[m] = *(const bf16x8*)(hv + off);
      }
#pragma unroll
      for (int n = 0; n < 2; ++n) {
        const int col = wid * 32 + n * 16 + fr;
        const size_t offb = ((size_t)kc * 256 + col) * 8;
        b_u[n] = *(const bf16x8*)(w2s + offb);
        b_v[n] = *(const bf16x8*)(w2s + (size_t)64 * 256 * 8 + offb);
      }
#pragma unroll
      for (int m = 0; m < 2; ++m)
#pragma unroll
        for (int n = 0; n < 2; ++n) {
          au[m][n] = MFMA16(a_u[m], b_u[n], au[m][n]);
          av[m][n] = MFMA16(a_v[m], b_v[n], av[m][n]);
        }
    }
  }

  // bias + per-row dot + reduction
  __shared__ float red[8][32];
  float bu[2], bv[2];
#pragma unroll
  for (int n = 0; n < 2; ++n) {
    const int col = wid * 32 + n * 16 + fr;
    bu[n] = ub2[col];
    bv[n] = ib2[col];
  }
#pragma unroll
  for (int m = 0; m < 2; ++m)
#pragma unroll
    for (int i = 0; i < 4; ++i) {
      float p = 0.0f;
#pragma unroll
      for (int n = 0; n < 2; ++n)
        p += (au[m][n][i] + bu[n]) * (av[m][n][i] + bv[n]);
      p += __shfl_xor(p, 1, 64);
      p += __shfl_xor(p, 2, 64);
      p += __shfl_xor(p, 4, 64);
      p += __shfl_xor(p, 8, 64);
      if (fr == 0) red[wid][m * 16 + fq * 4 + i] = p;
    }
  __syncthreads();
  if (tid < 32) {
    float s = 0.0f;
#pragma unroll
    for (int w = 0; w < 8; ++w) s += red[w][tid];
    out[row0 + tid] = s;
  }
}

extern "C" void kernel_launch(void* const* d_in, const int* in_sizes, int n_in,
                              void* d_out, int out_size, void* d_ws, size_t ws_size,
                              hipStream_t stream) {
  (void)in_sizes; (void)n_in; (void)out_size; (void)ws_size;
  const int*   x     = (const int*)d_in[0];
  const float* ulook = (const float*)d_in[1];
  const float* ilook = (const float*)d_in[2];
  const float* uW1   = (const float*)d_in[3];
  const float* ub1   = (const float*)d_in[4];
  const float* uW2   = (const float*)d_in[5];
  const float* ub2   = (const float*)d_in[6];
  const float* iW1   = (const float*)d_in[7];
  const float* ib1   = (const float*)d_in[8];
  const float* iW2   = (const float*)d_in[9];
  const float* ib2   = (const float*)d_in[10];
  float* out = (float*)d_out;

  // workspace layout (bytes):
  //   w1s: [2][272][512][8] bf16 = 4,456,448
  //   w2s: [2][64][256][8]  bf16 =   524,288  @ 4,456,448
  //   hsl: [2][8192*512]    bf16 = 16,777,216 @ 4,980,736
  char* ws = (char*)d_ws;
  unsigned short* w1s = (unsigned short*)(ws);
  unsigned short* w2s = (unsigned short*)(ws + 4456448);
  unsigned short* hsl = (unsigned short*)(ws + 4980736);

  ASAECF_tcast<<<dim3(544, 1, 2), 256, 0, stream>>>(uW1, iW1, w1s, 512, 9, ROWD, KC1, 1);
  ASAECF_tcast<<<dim3(64, 1, 2),  256, 0, stream>>>(uW2, iW2, w2s, 256, 8, HID, 64, 0);
  ASAECF_gemm1<<<dim3(256), 1024, 0, stream>>>(x, ulook, ilook, w1s, ub1, ib1, hsl);
  ASAECF_gemm2dot<<<dim3(256), 512, 0, stream>>>(hsl, w2s, ub2, ib2, out);
}